// Round 1
// baseline (2211.617 us; speedup 1.0000x reference)
//
#include <hip/hip_runtime.h>

#define N_PIX 1024
constexpr float SCALE = 0.17677669529663687f; // 32^-0.5

__device__ __forceinline__ float silu_f(float x) {
    return x / (1.f + __expf(-x));
}

// ---------------------------------------------------------------------------
// Generic fused conv1x1 (pointwise GEMM): out[b,o,n] = act(scale*Wx + bias) (+res)
// Tile: 64 outputs x 64 pixels per block; 256 threads; lane = pixel,
// wave owns 16 output channels. X staged in LDS; W via wave-uniform s_loads.
// Input channels can be split across two tensors (concat support).
// ---------------------------------------------------------------------------
__global__ __launch_bounds__(256) void conv1x1_k(
    const float* __restrict__ in0, int in0_ctot, int in0_coff, int n_c0,
    const float* __restrict__ in1, int in1_ctot, int in1_coff,
    const float* __restrict__ W, const float* __restrict__ sc, const float* __restrict__ bi,
    const float* __restrict__ res, int res_ctot, int res_coff,
    float* __restrict__ out, int out_ctot, int out_coff,
    int Cin, int act)
{
    __shared__ float XL[32 * 64];
    const int tid  = threadIdx.x;
    const int lane = tid & 63;
    const int wv   = __builtin_amdgcn_readfirstlane(tid >> 6);
    const int n0 = blockIdx.x * 64;
    const int o0 = blockIdx.y * 64;
    const int b  = blockIdx.z;

    float acc[16];
#pragma unroll
    for (int o = 0; o < 16; ++o) acc[o] = 0.f;

    for (int cc = 0; cc < Cin; cc += 32) {
        // stage 32 channels x 64 pixels (coalesced; conflict-free LDS writes)
#pragma unroll
        for (int s = 0; s < 8; ++s) {
            int lin = s * 256 + tid;
            int c = lin >> 6, j = lin & 63;
            int ch = cc + c;
            const float* src;
            if (ch < n_c0) src = in0 + ((size_t)(b * in0_ctot + in0_coff + ch)) * N_PIX;
            else           src = in1 + ((size_t)(b * in1_ctot + in1_coff + (ch - n_c0))) * N_PIX;
            XL[c * 64 + j] = src[n0 + j];
        }
        __syncthreads();

        // hoist X into registers (32 conflict-free ds_read_b32)
        float xv[32];
#pragma unroll
        for (int i = 0; i < 32; ++i) xv[i] = XL[i * 64 + lane];

        const float* wbase = W + (size_t)(o0 + wv * 16) * Cin + cc;
#pragma unroll
        for (int o = 0; o < 16; ++o) {
#pragma unroll
            for (int i = 0; i < 32; ++i)
                acc[o] = fmaf(wbase[(size_t)o * Cin + i], xv[i], acc[o]); // W: s_load
        }
        __syncthreads();
    }

    const int go0 = o0 + wv * 16;
#pragma unroll
    for (int o = 0; o < 16; ++o) {
        int go = go0 + o;
        float v = acc[o] * sc[go] + bi[go];
        if (act) v = silu_f(v);
        if (res) v += res[((size_t)(b * res_ctot + res_coff + go)) * N_PIX + n0 + lane];
        out[((size_t)(b * out_ctot + out_coff + go)) * N_PIX + n0 + lane] = v;
    }
}

// ---------------------------------------------------------------------------
// Attention pass A: per-row softmax stats (rowmax, 1/sum). One thread = one
// query row; K read via wave-uniform scalar loads (L2-resident).
// ---------------------------------------------------------------------------
__global__ __launch_bounds__(64) void attn_stats_k(
    const float* __restrict__ qkv, float* __restrict__ mxo, float* __restrict__ iso)
{
    const int lane = threadIdx.x;
    const int n = blockIdx.x * 64 + lane;
    const int h = blockIdx.y, b = blockIdx.z;
    const float* qb = qkv + ((size_t)(b * 512 + h * 128)) * N_PIX;
    const float* kb = qb + 32 * N_PIX;

    float qreg[32];
#pragma unroll
    for (int d = 0; d < 32; ++d) qreg[d] = qb[(size_t)d * N_PIX + n];

    float mx = -1e30f, sum = 0.f;
    for (int mc = 0; mc < N_PIX; mc += 16) {
        float sacc[16];
#pragma unroll
        for (int mi = 0; mi < 16; ++mi) sacc[mi] = 0.f;
#pragma unroll
        for (int d = 0; d < 32; ++d) {
            float qd = qreg[d];
#pragma unroll
            for (int mi = 0; mi < 16; ++mi)
                sacc[mi] = fmaf(qd, kb[(size_t)d * N_PIX + mc + mi], sacc[mi]);
        }
        float tm = sacc[0];
#pragma unroll
        for (int mi = 1; mi < 16; ++mi) tm = fmaxf(tm, sacc[mi]);
        tm *= SCALE;
        float mnew = fmaxf(mx, tm);
        float corr = __expf(mx - mnew);
        float psum = 0.f;
#pragma unroll
        for (int mi = 0; mi < 16; ++mi) psum += __expf(sacc[mi] * SCALE - mnew);
        sum = sum * corr + psum;
        mx = mnew;
    }
    size_t idx = ((size_t)(b * 4 + h)) * N_PIX + n;
    mxo[idx] = mx;
    iso[idx] = 1.f / sum;
}

// ---------------------------------------------------------------------------
// Attention pass B: recompute P tile (normalized, exp) into LDS, then PV.
// Block: 64 query rows x full m loop. lane = row; wave owns 16-m slice for P
// and 16-d slice for PV. K and V via wave-uniform scalar loads.
// ---------------------------------------------------------------------------
__global__ __launch_bounds__(256) void attn_pv_k(
    const float* __restrict__ qkv, const float* __restrict__ mxi, const float* __restrict__ isi,
    float* __restrict__ xa)
{
    __shared__ float PL[64 * 65];
    const int tid  = threadIdx.x;
    const int lane = tid & 63;
    const int wv   = __builtin_amdgcn_readfirstlane(tid >> 6);
    const int n0 = blockIdx.x * 64;
    const int h = blockIdx.y, b = blockIdx.z;
    const float* qb = qkv + ((size_t)(b * 512 + h * 128)) * N_PIX;
    const float* kb = qb + 32 * N_PIX;
    const float* vb = qb + 64 * N_PIX;

    float qreg[32];
#pragma unroll
    for (int d = 0; d < 32; ++d) qreg[d] = qb[(size_t)d * N_PIX + n0 + lane];
    size_t sidx = ((size_t)(b * 4 + h)) * N_PIX + n0 + lane;
    const float mxr = mxi[sidx];
    const float isr = isi[sidx];

    float acc[16];
#pragma unroll
    for (int o = 0; o < 16; ++o) acc[o] = 0.f;

    for (int m0 = 0; m0 < N_PIX; m0 += 64) {
        // phase P: row = lane, m = wv*16 + mi
        float sacc[16];
#pragma unroll
        for (int mi = 0; mi < 16; ++mi) sacc[mi] = 0.f;
#pragma unroll
        for (int d = 0; d < 32; ++d) {
            float qd = qreg[d];
#pragma unroll
            for (int mi = 0; mi < 16; ++mi)
                sacc[mi] = fmaf(qd, kb[(size_t)d * N_PIX + m0 + wv * 16 + mi], sacc[mi]);
        }
#pragma unroll
        for (int mi = 0; mi < 16; ++mi) {
            float p = __expf(sacc[mi] * SCALE - mxr) * isr;
            PL[(wv * 16 + mi) * 65 + lane] = p;
        }
        __syncthreads();

        // phase PV: d = wv*16 + o, row = lane
        for (int mq = 0; mq < 64; mq += 8) {
            float pv[8];
#pragma unroll
            for (int j = 0; j < 8; ++j) pv[j] = PL[(mq + j) * 65 + lane];
#pragma unroll
            for (int o = 0; o < 16; ++o) {
                const float* vrow = vb + (size_t)(wv * 16 + o) * N_PIX + m0 + mq;
#pragma unroll
                for (int j = 0; j < 8; ++j)
                    acc[o] = fmaf(pv[j], vrow[j], acc[o]); // V: s_load
            }
        }
        __syncthreads();
    }

#pragma unroll
    for (int o = 0; o < 16; ++o)
        xa[((size_t)(b * 256 + h * 64 + wv * 16 + o)) * N_PIX + n0 + lane] = acc[o];
}

// ---------------------------------------------------------------------------
// Depthwise 3x3 (SAME, zero-pad) on V, scale+bias, accumulated into xa.
// One block per (channel, batch) 32x32 plane staged in LDS.
// ---------------------------------------------------------------------------
__global__ __launch_bounds__(256) void dwconv_k(
    const float* __restrict__ qkv, const float* __restrict__ Wpe,
    const float* __restrict__ sc, const float* __restrict__ bi,
    float* __restrict__ xa)
{
    __shared__ float PL[1024];
    const int tid = threadIdx.x;
    const int c = blockIdx.x, b = blockIdx.y;
    const int qc = (c >> 6) * 128 + 64 + (c & 63); // v channel in qkv layout
    const float* src = qkv + ((size_t)(b * 512 + qc)) * N_PIX;
#pragma unroll
    for (int s = 0; s < 4; ++s) PL[s * 256 + tid] = src[s * 256 + tid];
    float w[9];
#pragma unroll
    for (int i = 0; i < 9; ++i) w[i] = Wpe[c * 9 + i];
    const float scv = sc[c], biv = bi[c];
    __syncthreads();

    float* dst = xa + ((size_t)(b * 256 + c)) * N_PIX;
#pragma unroll
    for (int s = 0; s < 4; ++s) {
        int pix = s * 256 + tid;
        int y = pix >> 5, x = pix & 31;
        float a = 0.f;
#pragma unroll
        for (int ky = 0; ky < 3; ++ky) {
            int yy = y + ky - 1;
            if (yy < 0 || yy > 31) continue;
#pragma unroll
            for (int kx = 0; kx < 3; ++kx) {
                int xx = x + kx - 1;
                if (xx < 0 || xx > 31) continue;
                a = fmaf(w[ky * 3 + kx], PL[yy * 32 + xx], a);
            }
        }
        dst[pix] += a * scv + biv;
    }
}

extern "C" void kernel_launch(void* const* d_in, const int* in_sizes, int n_in,
                              void* d_out, int out_size, void* d_ws, size_t ws_size,
                              hipStream_t stream)
{
    const float* x      = (const float*)d_in[0];
    const float* W_cv1  = (const float*)d_in[1];
    const float* s_cv1  = (const float*)d_in[2];
    const float* b_cv1  = (const float*)d_in[3];
    const float* W_qkv  = (const float*)d_in[4];
    const float* s_qkv  = (const float*)d_in[5];
    const float* b_qkv  = (const float*)d_in[6];
    const float* W_proj = (const float*)d_in[7];
    const float* s_proj = (const float*)d_in[8];
    const float* b_proj = (const float*)d_in[9];
    const float* W_pe   = (const float*)d_in[10];
    const float* s_pe   = (const float*)d_in[11];
    const float* b_pe   = (const float*)d_in[12];
    const float* W_ffn1 = (const float*)d_in[13];
    const float* s_ffn1 = (const float*)d_in[14];
    const float* b_ffn1 = (const float*)d_in[15];
    const float* W_ffn2 = (const float*)d_in[16];
    const float* s_ffn2 = (const float*)d_in[17];
    const float* b_ffn2 = (const float*)d_in[18];
    const float* W_cv2  = (const float*)d_in[19];
    const float* s_cv2  = (const float*)d_in[20];
    const float* b_cv2  = (const float*)d_in[21];

    float* ws   = (float*)d_ws;
    float* y    = ws;               // (16,512,1024) = 8388608 floats
    float* qkvb = y + 8388608;      // (16,512,1024) — later reused for ffn hidden
    float* xab  = qkvb + 8388608;   // (16,256,1024)
    float* bb2  = xab + 4194304;    // (16,256,1024)
    float* mx   = bb2 + 4194304;    // (16,4,1024)
    float* is   = mx + 65536;       // (16,4,1024)

    dim3 blk(256);

    // cv1: y = silu(W_cv1 x * s + b)
    conv1x1_k<<<dim3(16, 8, 16), blk, 0, stream>>>(
        x, 512, 0, 512, nullptr, 0, 0,
        W_cv1, s_cv1, b_cv1, nullptr, 0, 0, y, 512, 0, 512, 1);
    // qkv from bb = y[:,256:]
    conv1x1_k<<<dim3(16, 8, 16), blk, 0, stream>>>(
        y, 512, 256, 256, nullptr, 0, 0,
        W_qkv, s_qkv, b_qkv, nullptr, 0, 0, qkvb, 512, 0, 256, 0);
    // attention
    attn_stats_k<<<dim3(16, 4, 16), dim3(64), 0, stream>>>(qkvb, mx, is);
    attn_pv_k<<<dim3(16, 4, 16), blk, 0, stream>>>(qkvb, mx, is, xab);
    // xa += dwconv3(v)
    dwconv_k<<<dim3(256, 16), blk, 0, stream>>>(qkvb, W_pe, s_pe, b_pe, xab);
    // proj + residual bb -> bb2
    conv1x1_k<<<dim3(16, 4, 16), blk, 0, stream>>>(
        xab, 256, 0, 256, nullptr, 0, 0,
        W_proj, s_proj, b_proj, y, 512, 256, bb2, 256, 0, 256, 0);
    // ffn1 (hidden reuses qkv buffer)
    conv1x1_k<<<dim3(16, 8, 16), blk, 0, stream>>>(
        bb2, 256, 0, 256, nullptr, 0, 0,
        W_ffn1, s_ffn1, b_ffn1, nullptr, 0, 0, qkvb, 512, 0, 256, 1);
    // ffn2 + residual bb2 (in-place safe: one thread per element)
    conv1x1_k<<<dim3(16, 4, 16), blk, 0, stream>>>(
        qkvb, 512, 0, 512, nullptr, 0, 0,
        W_ffn2, s_ffn2, b_ffn2, bb2, 256, 0, bb2, 256, 0, 512, 0);
    // cv2 on concat(a = y[:,:256], bb2)
    conv1x1_k<<<dim3(16, 8, 16), blk, 0, stream>>>(
        y, 512, 0, 256, bb2, 256, 0,
        W_cv2, s_cv2, b_cv2, nullptr, 0, 0, (float*)d_out, 512, 0, 512, 1);
}

// Round 3
// 302.966 us; speedup vs baseline: 7.2999x; 7.2999x over previous
//
#include <hip/hip_runtime.h>

typedef unsigned short u16;
typedef __attribute__((ext_vector_type(8))) short short8;
typedef __attribute__((ext_vector_type(4))) float f32x4;
typedef __attribute__((ext_vector_type(4))) unsigned int uint4v;
typedef __attribute__((ext_vector_type(4))) unsigned short ushort4v;

#define N_PIX 1024
constexpr float SCALE = 0.17677669529663687f; // 32^-0.5

__device__ __forceinline__ float bf2f(u16 v) {
    unsigned u = ((unsigned)v) << 16;
    return __builtin_bit_cast(float, u);
}
__device__ __forceinline__ u16 f2bf(float f) {
    unsigned u = __builtin_bit_cast(unsigned, f);
    u += 0x7fff + ((u >> 16) & 1);
    return (u16)(u >> 16);
}
__device__ __forceinline__ float silu_f(float x) { return x / (1.f + __expf(-x)); }

__device__ __forceinline__ f32x4 mfma16(short8 a, short8 b, f32x4 c) {
    return __builtin_amdgcn_mfma_f32_16x16x32_bf16(a, b, c, 0, 0, 0);
}

__device__ __forceinline__ void gl_lds16(const u16* g, u16* l) {
    __builtin_amdgcn_global_load_lds(
        (const __attribute__((address_space(1))) unsigned int*)g,
        (__attribute__((address_space(3))) unsigned int*)l, 16, 0, 0);
}

// ---------------------------------------------------------------------------
// Weight fp32 -> bf16 conversion (6 segments, blockIdx.y selects)
// ---------------------------------------------------------------------------
__global__ void cvtw_k(const float* s0, u16* d0, int n0,
                       const float* s1, u16* d1, int n1,
                       const float* s2, u16* d2, int n2,
                       const float* s3, u16* d3, int n3,
                       const float* s4, u16* d4, int n4,
                       const float* s5, u16* d5, int n5)
{
    const float* sp = nullptr; u16* dp = nullptr; int n = 0;
    switch (blockIdx.y) {
        case 0: sp = s0; dp = d0; n = n0; break;
        case 1: sp = s1; dp = d1; n = n1; break;
        case 2: sp = s2; dp = d2; n = n2; break;
        case 3: sp = s3; dp = d3; n = n3; break;
        case 4: sp = s4; dp = d4; n = n4; break;
        case 5: sp = s5; dp = d5; n = n5; break;
    }
    for (int i = blockIdx.x * 256 + threadIdx.x; i < n; i += gridDim.x * 256)
        dp[i] = f2bf(sp[i]);
}

// ---------------------------------------------------------------------------
// x (b, 512, 1024) fp32 -> x_t (b, 1024, 512) bf16  (LDS-tiled transpose)
// ---------------------------------------------------------------------------
__global__ __launch_bounds__(256) void trans_k(const float* __restrict__ x, u16* __restrict__ xt)
{
    __shared__ float LT[64 * 65];
    const int tid = threadIdx.x;
    const int n0 = blockIdx.x * 64;
    const int c0 = blockIdx.y * 64;
    const int b  = blockIdx.z;
    const int w = tid >> 6, ln = tid & 63;
#pragma unroll
    for (int s = 0; s < 16; ++s) {
        int c = s * 4 + w;
        LT[c * 65 + ln] = x[((size_t)(b * 512 + c0 + c)) * N_PIX + n0 + ln];
    }
    __syncthreads();
#pragma unroll
    for (int s = 0; s < 16; ++s) {
        int n = s * 4 + w;
        xt[((size_t)(b * N_PIX + n0 + n)) * 512 + c0 + ln] = f2bf(LT[ln * 65 + n]);
    }
}

// ---------------------------------------------------------------------------
// bf16 MFMA GEMM for conv1x1 (m97-style): out_t[n][o] = act(s*Wx+b) (+res)
// Tile 128o x 128n, BK=32, 4 waves (2x2 quadrants of 64x64), dbuf LDS,
// global_load_lds width-16. Activations transposed (b, n, c).
// If out32: write fp32 original layout (b, o, n). If vsep: o-blocks are heads
// (128 ch) and the wr==1 half (V channels) is diverted to plane layout.
// ---------------------------------------------------------------------------
__global__ __launch_bounds__(256) void gemm_k(
    const u16* __restrict__ Xt, int xcs, int xcoff,
    const u16* __restrict__ Wb, int Cin,
    const float* __restrict__ sc, const float* __restrict__ bi,
    const u16* __restrict__ res, int rcs, int rcoff,
    u16* __restrict__ out, int ocs, int ocoff,
    float* __restrict__ out32,
    u16* __restrict__ vsep,
    int act)
{
    __shared__ __align__(16) u16 WT[2][128 * 32];
    __shared__ __align__(16) u16 XT[2][128 * 32];
    const int tid  = threadIdx.x;
    const int lane = tid & 63;
    const int w    = __builtin_amdgcn_readfirstlane(tid >> 6);
    const int wr = w >> 1, wc = w & 1;
    const int n0 = blockIdx.x * 128;
    const int o0 = blockIdx.y * 128;
    const int b  = blockIdx.z;
    const int l4 = lane >> 4, l15 = lane & 15;

    // staging: instr q covers rows q*16 + (lane>>2), k-granule lane&3
    const int srow0 = w * 16 + (lane >> 2);
    const int srow1 = (w + 4) * 16 + (lane >> 2);
    const int skc   = (lane & 3) * 8;
    const u16* wg0 = Wb + (size_t)(o0 + srow0) * Cin + skc;
    const u16* wg1 = Wb + (size_t)(o0 + srow1) * Cin + skc;
    const u16* xg0 = Xt + ((size_t)(b * N_PIX + n0 + srow0)) * xcs + xcoff + skc;
    const u16* xg1 = Xt + ((size_t)(b * N_PIX + n0 + srow1)) * xcs + xcoff + skc;

    f32x4 acc[4][4];
#pragma unroll
    for (int i = 0; i < 4; ++i)
#pragma unroll
        for (int j = 0; j < 4; ++j) acc[i][j] = (f32x4){0.f, 0.f, 0.f, 0.f};

    const int nk = Cin >> 5;
    gl_lds16(wg0, &WT[0][w * 512]);
    gl_lds16(wg1, &WT[0][(w + 4) * 512]);
    gl_lds16(xg0, &XT[0][w * 512]);
    gl_lds16(xg1, &XT[0][(w + 4) * 512]);
    __syncthreads();

    for (int kk = 0; kk < nk; ++kk) {
        const int cur = kk & 1;
        if (kk + 1 < nk) {
            const int cc = (kk + 1) << 5;
            gl_lds16(wg0 + cc, &WT[cur ^ 1][w * 512]);
            gl_lds16(wg1 + cc, &WT[cur ^ 1][(w + 4) * 512]);
            gl_lds16(xg0 + cc, &XT[cur ^ 1][w * 512]);
            gl_lds16(xg1 + cc, &XT[cur ^ 1][(w + 4) * 512]);
        }
        short8 af[4], bfr[4];
#pragma unroll
        for (int i = 0; i < 4; ++i)
            af[i] = *(const short8*)&WT[cur][(wr * 64 + i * 16 + l15) * 32 + l4 * 8];
#pragma unroll
        for (int j = 0; j < 4; ++j)
            bfr[j] = *(const short8*)&XT[cur][(wc * 64 + j * 16 + l15) * 32 + l4 * 8];
#pragma unroll
        for (int i = 0; i < 4; ++i)
#pragma unroll
            for (int j = 0; j < 4; ++j)
                acc[i][j] = mfma16(af[i], bfr[j], acc[i][j]);
        __syncthreads();
    }

    const bool is_v = (vsep != nullptr) && (wr == 1);
#pragma unroll
    for (int i = 0; i < 4; ++i) {
        const int ob = o0 + wr * 64 + i * 16 + l4 * 4;
        float s4[4], b4[4];
#pragma unroll
        for (int r = 0; r < 4; ++r) { s4[r] = sc[ob + r]; b4[r] = bi[ob + r]; }
#pragma unroll
        for (int j = 0; j < 4; ++j) {
            const int n = n0 + wc * 64 + j * 16 + l15;
            float v[4];
#pragma unroll
            for (int r = 0; r < 4; ++r) {
                v[r] = acc[i][j][r] * s4[r] + b4[r];
                if (act) v[r] = silu_f(v[r]);
            }
            if (out32) {
                const int Cout = gridDim.y * 128;
#pragma unroll
                for (int r = 0; r < 4; ++r)
                    out32[((size_t)b * Cout + ob + r) * N_PIX + n] = v[r];
            } else if (is_v) {
                const int hh = ob >> 7;
                const int dv = (ob & 127) - 64;
                u16* vp = vsep + (((size_t)(b * 4 + hh)) * 64 + dv) * N_PIX + n;
#pragma unroll
                for (int r = 0; r < 4; ++r) vp[r * N_PIX] = f2bf(v[r]);
            } else {
                const size_t base = ((size_t)(b * N_PIX + n)) * ocs + ocoff + ob;
                if (res) {
                    ushort4v rr = *(const ushort4v*)&res[((size_t)(b * N_PIX + n)) * rcs + rcoff + ob];
#pragma unroll
                    for (int r = 0; r < 4; ++r) v[r] += bf2f(rr[r]);
                }
                ushort4v pk;
#pragma unroll
                for (int r = 0; r < 4; ++r) pk[r] = f2bf(v[r]);
                *(ushort4v*)&out[base] = pk;
            }
        }
    }
}

// ---------------------------------------------------------------------------
// Fused flash attention: grid (nblk=16, h=4, b=16), 256 threads (4 waves x
// 16 q-rows). KV tile = 128. K/V reg-staged to padded LDS (all ds_read_b128
// <=2-way conflicts). Online softmax via 16-lane shfl_xor groups.
// ---------------------------------------------------------------------------
__global__ __launch_bounds__(256) void attn_k(
    const u16* __restrict__ qkvt, const u16* __restrict__ vsep,
    u16* __restrict__ xat)
{
    __shared__ __align__(16) u16 KT[128 * 40];   // [m][d] pad->40
    __shared__ __align__(16) u16 VT[64 * 136];   // [dv][m] pad->136
    __shared__ __align__(16) u16 PL[4 * 16 * 136];
    const int tid  = threadIdx.x;
    const int lane = tid & 63;
    const int w    = __builtin_amdgcn_readfirstlane(tid >> 6);
    const int l4 = lane >> 4, l15 = lane & 15;
    const int h = blockIdx.y, b = blockIdx.z;
    const int n0w = blockIdx.x * 64 + w * 16;
    u16* PLw = PL + w * 16 * 136;

    const short8 qf = *(const short8*)&qkvt[((size_t)(b * N_PIX + n0w + l15)) * 512 + h * 128 + l4 * 8];

    float mrun[4], lrun[4];
#pragma unroll
    for (int r = 0; r < 4; ++r) { mrun[r] = -1e30f; lrun[r] = 0.f; }
    f32x4 accv[4];
#pragma unroll
    for (int d = 0; d < 4; ++d) accv[d] = (f32x4){0.f, 0.f, 0.f, 0.f};
    const f32x4 z4 = {0.f, 0.f, 0.f, 0.f};

    const int smr = tid >> 2, skc = (tid & 3) * 8;    // K staging
    const int sdv = tid >> 4, sg = (tid & 15) * 8;    // V staging

    for (int t8 = 0; t8 < 8; ++t8) {
        const int m0 = t8 * 128;
        // stage K tile (128 x 32)
        *(uint4v*)&KT[smr * 40 + skc] =
            *(const uint4v*)&qkvt[((size_t)(b * N_PIX + m0 + smr)) * 512 + h * 128 + 32 + skc];
        *(uint4v*)&KT[(smr + 64) * 40 + skc] =
            *(const uint4v*)&qkvt[((size_t)(b * N_PIX + m0 + 64 + smr)) * 512 + h * 128 + 32 + skc];
        // stage V tile (64 dv x 128 m), plane layout source
#pragma unroll
        for (int rr = 0; rr < 4; ++rr)
            *(uint4v*)&VT[(rr * 16 + sdv) * 136 + sg] =
                *(const uint4v*)&vsep[(((size_t)(b * 4 + h)) * 64 + rr * 16 + sdv) * N_PIX + m0 + sg];
        __syncthreads();

        // QK^T
        f32x4 s[8];
#pragma unroll
        for (int mt = 0; mt < 8; ++mt) {
            short8 kf = *(const short8*)&KT[(mt * 16 + l15) * 40 + l4 * 8];
            s[mt] = mfma16(qf, kf, z4);
        }
        // online softmax
        float tm[4];
#pragma unroll
        for (int r = 0; r < 4; ++r) {
            float m_ = s[0][r];
#pragma unroll
            for (int mt = 1; mt < 8; ++mt) m_ = fmaxf(m_, s[mt][r]);
            m_ = fmaxf(m_, __shfl_xor(m_, 1));
            m_ = fmaxf(m_, __shfl_xor(m_, 2));
            m_ = fmaxf(m_, __shfl_xor(m_, 4));
            m_ = fmaxf(m_, __shfl_xor(m_, 8));
            tm[r] = m_ * SCALE;
        }
#pragma unroll
        for (int r = 0; r < 4; ++r) {
            float mnew = fmaxf(mrun[r], tm[r]);
            float corr = __expf(mrun[r] - mnew);
            mrun[r] = mnew;
            lrun[r] *= corr;
#pragma unroll
            for (int d = 0; d < 4; ++d) accv[d][r] *= corr;
        }
#pragma unroll
        for (int mt = 0; mt < 8; ++mt)
#pragma unroll
            for (int r = 0; r < 4; ++r) {
                float p = __expf(s[mt][r] * SCALE - mrun[r]);
                lrun[r] += p;
                PLw[(l4 * 4 + r) * 136 + mt * 16 + l15] = f2bf(p);
            }
        // PV
#pragma unroll
        for (int mq = 0; mq < 4; ++mq) {
            short8 pa = *(const short8*)&PLw[l15 * 136 + mq * 32 + l4 * 8];
#pragma unroll
            for (int d = 0; d < 4; ++d) {
                short8 vf = *(const short8*)&VT[(d * 16 + l15) * 136 + mq * 32 + l4 * 8];
                accv[d] = mfma16(pa, vf, accv[d]);
            }
        }
        __syncthreads();
    }

#pragma unroll
    for (int r = 0; r < 4; ++r) {
        float sum = lrun[r];
        sum += __shfl_xor(sum, 1);
        sum += __shfl_xor(sum, 2);
        sum += __shfl_xor(sum, 4);
        sum += __shfl_xor(sum, 8);
        lrun[r] = 1.f / sum;
    }
#pragma unroll
    for (int d = 0; d < 4; ++d)
#pragma unroll
        for (int r = 0; r < 4; ++r) {
            const int n = n0w + l4 * 4 + r;
            xat[((size_t)(b * N_PIX + n)) * 256 + h * 64 + d * 16 + l15] =
                f2bf(accv[d][r] * lrun[r]);
        }
}

// ---------------------------------------------------------------------------
// Depthwise 3x3 on V planes (v_sep), scale+bias, accumulate into xa_t.
// grid (ystrip=16, b=16); thread = channel; rows in registers.
// ---------------------------------------------------------------------------
__global__ __launch_bounds__(256) void pe_k(
    const u16* __restrict__ vsep, const float* __restrict__ Wpe,
    const float* __restrict__ spe, const float* __restrict__ bpe,
    u16* __restrict__ xat)
{
    const int t  = threadIdx.x;          // channel
    const int y0 = blockIdx.x * 2;
    const int b  = blockIdx.y;
    const u16* vp = vsep + ((size_t)(b * 256 + t)) * N_PIX;

    float rv[128];
#pragma unroll
    for (int rr = 0; rr < 4; ++rr) {
        const int yy = y0 - 1 + rr;
        if (yy >= 0 && yy < 32) {
#pragma unroll
            for (int g = 0; g < 4; ++g) {
                uint4v u = *(const uint4v*)&vp[yy * 32 + g * 8];
#pragma unroll
                for (int e = 0; e < 4; ++e) {
                    rv[rr * 32 + g * 8 + e * 2]     = bf2f((u16)(u[e] & 0xffff));
                    rv[rr * 32 + g * 8 + e * 2 + 1] = bf2f((u16)(u[e] >> 16));
                }
            }
        } else {
#pragma unroll
            for (int j = 0; j < 32; ++j) rv[rr * 32 + j] = 0.f;
        }
    }
    float w9[9];
#pragma unroll
    for (int i = 0; i < 9; ++i) w9[i] = Wpe[t * 9 + i];
    const float scv = spe[t], biv = bpe[t];
    u16* xp = xat + ((size_t)(b * N_PIX)) * 256 + t;

#pragma unroll
    for (int py = 0; py < 2; ++py)
#pragma unroll
        for (int px = 0; px < 32; ++px) {
            float a = 0.f;
#pragma unroll
            for (int ky = 0; ky < 3; ++ky) {
                const int lr = py + ky;
#pragma unroll
                for (int kx = 0; kx < 3; ++kx) {
                    const int xx = px + kx - 1;
                    if (xx >= 0 && xx < 32)
                        a = fmaf(w9[ky * 3 + kx], rv[lr * 32 + xx], a);
                }
            }
            const int n = (y0 + py) * 32 + px;
            u16* p = xp + (size_t)n * 256;
            *p = f2bf(bf2f(*p) + a * scv + biv);
        }
}

extern "C" void kernel_launch(void* const* d_in, const int* in_sizes, int n_in,
                              void* d_out, int out_size, void* d_ws, size_t ws_size,
                              hipStream_t stream)
{
    const float* x      = (const float*)d_in[0];
    const float* W_cv1  = (const float*)d_in[1];
    const float* s_cv1  = (const float*)d_in[2];
    const float* b_cv1  = (const float*)d_in[3];
    const float* W_qkv  = (const float*)d_in[4];
    const float* s_qkv  = (const float*)d_in[5];
    const float* b_qkv  = (const float*)d_in[6];
    const float* W_proj = (const float*)d_in[7];
    const float* s_proj = (const float*)d_in[8];
    const float* b_proj = (const float*)d_in[9];
    const float* W_pe   = (const float*)d_in[10];
    const float* s_pe   = (const float*)d_in[11];
    const float* b_pe   = (const float*)d_in[12];
    const float* W_ffn1 = (const float*)d_in[13];
    const float* s_ffn1 = (const float*)d_in[14];
    const float* b_ffn1 = (const float*)d_in[15];
    const float* W_ffn2 = (const float*)d_in[16];
    const float* s_ffn2 = (const float*)d_in[17];
    const float* b_ffn2 = (const float*)d_in[18];
    const float* W_cv2  = (const float*)d_in[19];
    const float* s_cv2  = (const float*)d_in[20];
    const float* b_cv2  = (const float*)d_in[21];

    u16* ws = (u16*)d_ws;
    u16* xt      = ws;                    // 16*1024*512
    u16* yt      = xt + 8388608;
    u16* qkvt    = yt + 8388608;
    u16* fft     = qkvt + 8388608;
    u16* vsep    = fft + 8388608;         // 16*256*1024
    u16* xat     = vsep + 4194304;        // 16*1024*256
    u16* wb_cv1  = xat + 4194304;
    u16* wb_qkv  = wb_cv1 + 262144;
    u16* wb_proj = wb_qkv + 131072;
    u16* wb_ffn1 = wb_proj + 65536;
    u16* wb_ffn2 = wb_ffn1 + 131072;
    u16* wb_cv2  = wb_ffn2 + 131072;

    cvtw_k<<<dim3(64, 6), 256, 0, stream>>>(
        W_cv1, wb_cv1, 512 * 512, W_qkv, wb_qkv, 512 * 256,
        W_proj, wb_proj, 256 * 256, W_ffn1, wb_ffn1, 512 * 256,
        W_ffn2, wb_ffn2, 256 * 512, W_cv2, wb_cv2, 512 * 512);
    trans_k<<<dim3(16, 8, 16), 256, 0, stream>>>(x, xt);

    // cv1: y_t = silu(W_cv1 x)   (512 out)
    gemm_k<<<dim3(8, 4, 16), 256, 0, stream>>>(
        xt, 512, 0, wb_cv1, 512, s_cv1, b_cv1,
        nullptr, 0, 0, yt, 512, 0, nullptr, nullptr, 1);
    // qkv from bb = y_t[:,:,256:]; V channels diverted to plane layout
    gemm_k<<<dim3(8, 4, 16), 256, 0, stream>>>(
        yt, 512, 256, wb_qkv, 256, s_qkv, b_qkv,
        nullptr, 0, 0, qkvt, 512, 0, nullptr, vsep, 0);
    // fused flash attention -> xa_t
    attn_k<<<dim3(16, 4, 16), 256, 0, stream>>>(qkvt, vsep, xat);
    // xa_t += dwconv3(v)
    pe_k<<<dim3(16, 16), 256, 0, stream>>>(vsep, W_pe, s_pe, b_pe, xat);
    // proj + residual, in-place into y_t[:,:,256:]
    gemm_k<<<dim3(8, 2, 16), 256, 0, stream>>>(
        xat, 256, 0, wb_proj, 256, s_proj, b_proj,
        yt, 512, 256, yt, 512, 256, nullptr, nullptr, 0);
    // ffn1
    gemm_k<<<dim3(8, 4, 16), 256, 0, stream>>>(
        yt, 512, 256, wb_ffn1, 256, s_ffn1, b_ffn1,
        nullptr, 0, 0, fft, 512, 0, nullptr, nullptr, 1);
    // ffn2 + residual, in-place into y_t[:,:,256:]
    gemm_k<<<dim3(8, 2, 16), 256, 0, stream>>>(
        fft, 512, 0, wb_ffn2, 512, s_ffn2, b_ffn2,
        yt, 512, 256, yt, 512, 256, nullptr, nullptr, 0);
    // cv2 on concat(a, bb) = y_t[:,:,0:512] -> d_out fp32 (b, 512, 1024)
    gemm_k<<<dim3(8, 4, 16), 256, 0, stream>>>(
        yt, 512, 0, wb_cv2, 512, s_cv2, b_cv2,
        nullptr, 0, 0, nullptr, 0, 0, (float*)d_out, nullptr, 1);
}

// Round 7
// 284.226 us; speedup vs baseline: 7.7812x; 1.0659x over previous
//
#include <hip/hip_runtime.h>

typedef unsigned short u16;
typedef __attribute__((ext_vector_type(8))) short short8;
typedef __attribute__((ext_vector_type(4))) float f32x4;
typedef __attribute__((ext_vector_type(4))) unsigned int uint4v;
typedef __attribute__((ext_vector_type(4))) unsigned short ushort4v;

#define N_PIX 1024
constexpr float SCALE = 0.17677669529663687f; // 32^-0.5

__device__ __forceinline__ float bf2f(u16 v) {
    unsigned u = ((unsigned)v) << 16;
    return __builtin_bit_cast(float, u);
}
__device__ __forceinline__ u16 f2bf(float f) {
    unsigned u = __builtin_bit_cast(unsigned, f);
    u += 0x7fff + ((u >> 16) & 1);
    return (u16)(u >> 16);
}
__device__ __forceinline__ float silu_f(float x) { return x / (1.f + __expf(-x)); }

__device__ __forceinline__ f32x4 mfma16(short8 a, short8 b, f32x4 c) {
    return __builtin_amdgcn_mfma_f32_16x16x32_bf16(a, b, c, 0, 0, 0);
}

__device__ __forceinline__ void gl_lds16(const u16* g, u16* l) {
    __builtin_amdgcn_global_load_lds(
        (const __attribute__((address_space(1))) unsigned int*)g,
        (__attribute__((address_space(3))) unsigned int*)l, 16, 0, 0);
}

// ---------------------------------------------------------------------------
// Weight fp32 -> bf16 conversion (6 segments, blockIdx.y selects)
// ---------------------------------------------------------------------------
__global__ void cvtw_k(const float* s0, u16* d0, int n0,
                       const float* s1, u16* d1, int n1,
                       const float* s2, u16* d2, int n2,
                       const float* s3, u16* d3, int n3,
                       const float* s4, u16* d4, int n4,
                       const float* s5, u16* d5, int n5)
{
    const float* sp = nullptr; u16* dp = nullptr; int n = 0;
    switch (blockIdx.y) {
        case 0: sp = s0; dp = d0; n = n0; break;
        case 1: sp = s1; dp = d1; n = n1; break;
        case 2: sp = s2; dp = d2; n = n2; break;
        case 3: sp = s3; dp = d3; n = n3; break;
        case 4: sp = s4; dp = d4; n = n4; break;
        case 5: sp = s5; dp = d5; n = n5; break;
    }
    for (int i = blockIdx.x * 256 + threadIdx.x; i < n; i += gridDim.x * 256)
        dp[i] = f2bf(sp[i]);
}

// ---------------------------------------------------------------------------
// x (b, 512, 1024) fp32 -> x_t (b, 1024, 512) bf16  (LDS-tiled transpose)
// ---------------------------------------------------------------------------
__global__ __launch_bounds__(256) void trans_k(const float* __restrict__ x, u16* __restrict__ xt)
{
    __shared__ float LT[64 * 65];
    const int tid = threadIdx.x;
    const int n0 = blockIdx.x * 64;
    const int c0 = blockIdx.y * 64;
    const int b  = blockIdx.z;
    const int w = tid >> 6, ln = tid & 63;
#pragma unroll
    for (int s = 0; s < 16; ++s) {
        int c = s * 4 + w;
        LT[c * 65 + ln] = x[((size_t)(b * 512 + c0 + c)) * N_PIX + n0 + ln];
    }
    __syncthreads();
#pragma unroll
    for (int s = 0; s < 16; ++s) {
        int n = s * 4 + w;
        xt[((size_t)(b * N_PIX + n0 + n)) * 512 + c0 + ln] = f2bf(LT[ln * 65 + n]);
    }
}

// ---------------------------------------------------------------------------
// bf16 MFMA GEMM for conv1x1 (m97-style): out_t[n][o] = act(s*Wx+b) (+res)
// Tile 128o x 128n, BK=32, 4 waves (2x2 quadrants of 64x64), dbuf LDS,
// global_load_lds width-16. Activations transposed (b, n, c).
// ---------------------------------------------------------------------------
__global__ __launch_bounds__(256) void gemm_k(
    const u16* __restrict__ Xt, int xcs, int xcoff,
    const u16* __restrict__ Wb, int Cin,
    const float* __restrict__ sc, const float* __restrict__ bi,
    const u16* __restrict__ res, int rcs, int rcoff,
    u16* __restrict__ out, int ocs, int ocoff,
    float* __restrict__ out32,
    u16* __restrict__ vsep,
    int act)
{
    __shared__ __align__(16) u16 WT[2][128 * 32];
    __shared__ __align__(16) u16 XT[2][128 * 32];
    const int tid  = threadIdx.x;
    const int lane = tid & 63;
    const int w    = __builtin_amdgcn_readfirstlane(tid >> 6);
    const int wr = w >> 1, wc = w & 1;
    const int n0 = blockIdx.x * 128;
    const int o0 = blockIdx.y * 128;
    const int b  = blockIdx.z;
    const int l4 = lane >> 4, l15 = lane & 15;

    const int srow0 = w * 16 + (lane >> 2);
    const int srow1 = (w + 4) * 16 + (lane >> 2);
    const int skc   = (lane & 3) * 8;
    const u16* wg0 = Wb + (size_t)(o0 + srow0) * Cin + skc;
    const u16* wg1 = Wb + (size_t)(o0 + srow1) * Cin + skc;
    const u16* xg0 = Xt + ((size_t)(b * N_PIX + n0 + srow0)) * xcs + xcoff + skc;
    const u16* xg1 = Xt + ((size_t)(b * N_PIX + n0 + srow1)) * xcs + xcoff + skc;

    f32x4 acc[4][4];
#pragma unroll
    for (int i = 0; i < 4; ++i)
#pragma unroll
        for (int j = 0; j < 4; ++j) acc[i][j] = (f32x4){0.f, 0.f, 0.f, 0.f};

    const int nk = Cin >> 5;
    gl_lds16(wg0, &WT[0][w * 512]);
    gl_lds16(wg1, &WT[0][(w + 4) * 512]);
    gl_lds16(xg0, &XT[0][w * 512]);
    gl_lds16(xg1, &XT[0][(w + 4) * 512]);
    __syncthreads();

    for (int kk = 0; kk < nk; ++kk) {
        const int cur = kk & 1;
        if (kk + 1 < nk) {
            const int cc = (kk + 1) << 5;
            gl_lds16(wg0 + cc, &WT[cur ^ 1][w * 512]);
            gl_lds16(wg1 + cc, &WT[cur ^ 1][(w + 4) * 512]);
            gl_lds16(xg0 + cc, &XT[cur ^ 1][w * 512]);
            gl_lds16(xg1 + cc, &XT[cur ^ 1][(w + 4) * 512]);
        }
        short8 af[4], bfr[4];
#pragma unroll
        for (int i = 0; i < 4; ++i)
            af[i] = *(const short8*)&WT[cur][(wr * 64 + i * 16 + l15) * 32 + l4 * 8];
#pragma unroll
        for (int j = 0; j < 4; ++j)
            bfr[j] = *(const short8*)&XT[cur][(wc * 64 + j * 16 + l15) * 32 + l4 * 8];
#pragma unroll
        for (int i = 0; i < 4; ++i)
#pragma unroll
            for (int j = 0; j < 4; ++j)
                acc[i][j] = mfma16(af[i], bfr[j], acc[i][j]);
        __syncthreads();
    }

    const bool is_v = (vsep != nullptr) && (wr == 1);
#pragma unroll
    for (int i = 0; i < 4; ++i) {
        const int ob = o0 + wr * 64 + i * 16 + l4 * 4;
        float s4[4], b4[4];
#pragma unroll
        for (int r = 0; r < 4; ++r) { s4[r] = sc[ob + r]; b4[r] = bi[ob + r]; }
#pragma unroll
        for (int j = 0; j < 4; ++j) {
            const int n = n0 + wc * 64 + j * 16 + l15;
            float v[4];
#pragma unroll
            for (int r = 0; r < 4; ++r) {
                v[r] = acc[i][j][r] * s4[r] + b4[r];
                if (act) v[r] = silu_f(v[r]);
            }
            if (out32) {
                const int Cout = gridDim.y * 128;
#pragma unroll
                for (int r = 0; r < 4; ++r)
                    out32[((size_t)b * Cout + ob + r) * N_PIX + n] = v[r];
            } else if (is_v) {
                const int hh = ob >> 7;
                const int dv = (ob & 127) - 64;
                u16* vp = vsep + (((size_t)(b * 4 + hh)) * 64 + dv) * N_PIX + n;
#pragma unroll
                for (int r = 0; r < 4; ++r) vp[r * N_PIX] = f2bf(v[r]);
            } else {
                const size_t base = ((size_t)(b * N_PIX + n)) * ocs + ocoff + ob;
                if (res) {
                    ushort4v rr = *(const ushort4v*)&res[((size_t)(b * N_PIX + n)) * rcs + rcoff + ob];
#pragma unroll
                    for (int r = 0; r < 4; ++r) v[r] += bf2f(rr[r]);
                }
                ushort4v pk;
#pragma unroll
                for (int r = 0; r < 4; ++r) pk[r] = f2bf(v[r]);
                *(ushort4v*)&out[base] = pk;
            }
        }
    }
}

// ---------------------------------------------------------------------------
// Fused flash attention, latency-hidden version.
// grid (16, 4, 16), 256 threads = 4 waves x 16 q-rows. KV tile = 64,
// double-buffered K/V LDS with async-STAGE split (T14): ds_write staged regs,
// issue next tile's global loads (latency hides under barrier + compute),
// ONE barrier per tile. 37.9KB LDS -> 4 blocks/CU. setprio around MFMA (T5).
// ---------------------------------------------------------------------------
__global__ __launch_bounds__(256) void attn_k(
    const u16* __restrict__ qkvt, const u16* __restrict__ vsep,
    u16* __restrict__ xat)
{
    __shared__ __align__(16) u16 KT[2][64 * 40];   // [m][d] pad 40
    __shared__ __align__(16) u16 VT[2][64 * 72];   // [dv][m] pad 72
    __shared__ __align__(16) u16 PL[4 * 16 * 72];  // per-wave P rows
    const int tid  = threadIdx.x;
    const int lane = tid & 63;
    const int w    = __builtin_amdgcn_readfirstlane(tid >> 6);
    const int l4 = lane >> 4, l15 = lane & 15;
    const int h = blockIdx.y, b = blockIdx.z;
    const int n0w = blockIdx.x * 64 + w * 16;
    u16* PLw = PL + w * 16 * 72;

    const short8 qf = *(const short8*)&qkvt[((size_t)(b * N_PIX + n0w + l15)) * 512 + h * 128 + l4 * 8];

    // staging coordinates
    const int skr = tid >> 2, skc = (tid & 3) * 8;          // K: row, d-col
    const int svd = tid >> 3, svm = (tid & 7) * 8;          // V: dv (0..31), m-col
    const u16* kgbase = qkvt + ((size_t)(b * N_PIX + skr)) * 512 + h * 128 + 32 + skc;
    const u16* vgbase = vsep + (((size_t)(b * 4 + h)) * 64 + svd) * N_PIX + svm;

    float mrun[4], lrun[4];
#pragma unroll
    for (int r = 0; r < 4; ++r) { mrun[r] = -1e30f; lrun[r] = 0.f; }
    f32x4 accv[4];
#pragma unroll
    for (int d = 0; d < 4; ++d) accv[d] = (f32x4){0.f, 0.f, 0.f, 0.f};
    const f32x4 z4 = {0.f, 0.f, 0.f, 0.f};

    // prologue: tile 0 into regs
    uint4v kreg = *(const uint4v*)(kgbase);
    uint4v vr0  = *(const uint4v*)(vgbase);
    uint4v vr1  = *(const uint4v*)(vgbase + 32 * N_PIX);

    for (int t = 0; t < 16; ++t) {
        const int cur = t & 1;
        // write tile t (regs) into buf cur
        *(uint4v*)&KT[cur][skr * 40 + skc] = kreg;
        *(uint4v*)&VT[cur][svd * 72 + svm] = vr0;
        *(uint4v*)&VT[cur][(svd + 32) * 72 + svm] = vr1;
        // issue tile t+1 loads; latency hides under barrier + compute
        if (t < 15) {
            const int m1 = (t + 1) * 64;
            kreg = *(const uint4v*)(kgbase + (size_t)m1 * 512);
            vr0  = *(const uint4v*)(vgbase + m1);
            vr1  = *(const uint4v*)(vgbase + 32 * N_PIX + m1);
        }
        __syncthreads();

        // QK^T (4 x 16-key groups)
        f32x4 s[4];
        __builtin_amdgcn_s_setprio(1);
#pragma unroll
        for (int mt = 0; mt < 4; ++mt) {
            short8 kf = *(const short8*)&KT[cur][(mt * 16 + l15) * 40 + l4 * 8];
            s[mt] = mfma16(qf, kf, z4);
        }
        __builtin_amdgcn_s_setprio(0);

        // online softmax (rows r, 16-lane groups)
        float tm[4];
#pragma unroll
        for (int r = 0; r < 4; ++r) {
            float m_ = fmaxf(fmaxf(s[0][r], s[1][r]), fmaxf(s[2][r], s[3][r]));
            m_ = fmaxf(m_, __shfl_xor(m_, 1));
            m_ = fmaxf(m_, __shfl_xor(m_, 2));
            m_ = fmaxf(m_, __shfl_xor(m_, 4));
            m_ = fmaxf(m_, __shfl_xor(m_, 8));
            tm[r] = m_ * SCALE;
        }
#pragma unroll
        for (int r = 0; r < 4; ++r) {
            float mnew = fmaxf(mrun[r], tm[r]);
            float corr = __expf(mrun[r] - mnew);
            mrun[r] = mnew;
            lrun[r] *= corr;
#pragma unroll
            for (int d = 0; d < 4; ++d) accv[d][r] *= corr;
        }
#pragma unroll
        for (int mt = 0; mt < 4; ++mt)
#pragma unroll
            for (int r = 0; r < 4; ++r) {
                float p = __expf(s[mt][r] * SCALE - mrun[r]);
                lrun[r] += p;
                PLw[(l4 * 4 + r) * 72 + mt * 16 + l15] = f2bf(p);
            }

        // PV (2 x 32-key slices)
        __builtin_amdgcn_s_setprio(1);
#pragma unroll
        for (int mq = 0; mq < 2; ++mq) {
            short8 pa = *(const short8*)&PLw[l15 * 72 + mq * 32 + l4 * 8];
#pragma unroll
            for (int d = 0; d < 4; ++d) {
                short8 vf = *(const short8*)&VT[cur][(d * 16 + l15) * 72 + mq * 32 + l4 * 8];
                accv[d] = mfma16(pa, vf, accv[d]);
            }
        }
        __builtin_amdgcn_s_setprio(0);
        // no trailing barrier: next iteration writes buf cur^1, whose readers
        // all finished before this iteration's barrier.
    }

#pragma unroll
    for (int r = 0; r < 4; ++r) {
        float sum = lrun[r];
        sum += __shfl_xor(sum, 1);
        sum += __shfl_xor(sum, 2);
        sum += __shfl_xor(sum, 4);
        sum += __shfl_xor(sum, 8);
        lrun[r] = 1.f / sum;
    }
#pragma unroll
    for (int d = 0; d < 4; ++d)
#pragma unroll
        for (int r = 0; r < 4; ++r) {
            const int n = n0w + l4 * 4 + r;
            xat[((size_t)(b * N_PIX + n)) * 256 + h * 64 + d * 16 + l15] =
                f2bf(accv[d][r] * lrun[r]);
        }
}

// ---------------------------------------------------------------------------
// Depthwise 3x3 on V planes (v_sep), scale+bias, accumulate into xa_t.
// ---------------------------------------------------------------------------
__global__ __launch_bounds__(256) void pe_k(
    const u16* __restrict__ vsep, const float* __restrict__ Wpe,
    const float* __restrict__ spe, const float* __restrict__ bpe,
    u16* __restrict__ xat)
{
    const int t  = threadIdx.x;          // channel
    const int y0 = blockIdx.x * 2;
    const int b  = blockIdx.y;
    const u16* vp = vsep + ((size_t)(b * 256 + t)) * N_PIX;

    float rv[128];
#pragma unroll
    for (int rr = 0; rr < 4; ++rr) {
        const int yy = y0 - 1 + rr;
        if (yy >= 0 && yy < 32) {
#pragma unroll
            for (int g = 0; g < 4; ++g) {
                uint4v u = *(const uint4v*)&vp[yy * 32 + g * 8];
#pragma unroll
                for (int e = 0; e < 4; ++e) {
                    rv[rr * 32 + g * 8 + e * 2]     = bf2f((u16)(u[e] & 0xffff));
                    rv[rr * 32 + g * 8 + e * 2 + 1] = bf2f((u16)(u[e] >> 16));
                }
            }
        } else {
#pragma unroll
            for (int j = 0; j < 32; ++j) rv[rr * 32 + j] = 0.f;
        }
    }
    float w9[9];
#pragma unroll
    for (int i = 0; i < 9; ++i) w9[i] = Wpe[t * 9 + i];
    const float scv = spe[t], biv = bpe[t];
    u16* xp = xat + ((size_t)(b * N_PIX)) * 256 + t;

#pragma unroll
    for (int py = 0; py < 2; ++py)
#pragma unroll
        for (int px = 0; px < 32; ++px) {
            float a = 0.f;
#pragma unroll
            for (int ky = 0; ky < 3; ++ky) {
                const int lr = py + ky;
#pragma unroll
                for (int kx = 0; kx < 3; ++kx) {
                    const int xx = px + kx - 1;
                    if (xx >= 0 && xx < 32)
                        a = fmaf(w9[ky * 3 + kx], rv[lr * 32 + xx], a);
                }
            }
            const int n = (y0 + py) * 32 + px;
            u16* p = xp + (size_t)n * 256;
            *p = f2bf(bf2f(*p) + a * scv + biv);
        }
}

extern "C" void kernel_launch(void* const* d_in, const int* in_sizes, int n_in,
                              void* d_out, int out_size, void* d_ws, size_t ws_size,
                              hipStream_t stream)
{
    const float* x      = (const float*)d_in[0];
    const float* W_cv1  = (const float*)d_in[1];
    const float* s_cv1  = (const float*)d_in[2];
    const float* b_cv1  = (const float*)d_in[3];
    const float* W_qkv  = (const float*)d_in[4];
    const float* s_qkv  = (const float*)d_in[5];
    const float* b_qkv  = (const float*)d_in[6];
    const float* W_proj = (const float*)d_in[7];
    const float* s_proj = (const float*)d_in[8];
    const float* b_proj = (const float*)d_in[9];
    const float* W_pe   = (const float*)d_in[10];
    const float* s_pe   = (const float*)d_in[11];
    const float* b_pe   = (const float*)d_in[12];
    const float* W_ffn1 = (const float*)d_in[13];
    const float* s_ffn1 = (const float*)d_in[14];
    const float* b_ffn1 = (const float*)d_in[15];
    const float* W_ffn2 = (const float*)d_in[16];
    const float* s_ffn2 = (const float*)d_in[17];
    const float* b_ffn2 = (const float*)d_in[18];
    const float* W_cv2  = (const float*)d_in[19];
    const float* s_cv2  = (const float*)d_in[20];
    const float* b_cv2  = (const float*)d_in[21];

    u16* ws = (u16*)d_ws;
    u16* xt      = ws;                    // 16*1024*512
    u16* yt      = xt + 8388608;
    u16* qkvt    = yt + 8388608;
    u16* fft     = qkvt + 8388608;
    u16* vsep    = fft + 8388608;         // 16*256*1024
    u16* xat     = vsep + 4194304;        // 16*1024*256
    u16* wb_cv1  = xat + 4194304;
    u16* wb_qkv  = wb_cv1 + 262144;
    u16* wb_proj = wb_qkv + 131072;
    u16* wb_ffn1 = wb_proj + 65536;
    u16* wb_ffn2 = wb_ffn1 + 131072;
    u16* wb_cv2  = wb_ffn2 + 131072;

    cvtw_k<<<dim3(64, 6), 256, 0, stream>>>(
        W_cv1, wb_cv1, 512 * 512, W_qkv, wb_qkv, 512 * 256,
        W_proj, wb_proj, 256 * 256, W_ffn1, wb_ffn1, 512 * 256,
        W_ffn2, wb_ffn2, 256 * 512, W_cv2, wb_cv2, 512 * 512);
    trans_k<<<dim3(16, 8, 16), 256, 0, stream>>>(x, xt);

    // cv1: y_t = silu(W_cv1 x)   (512 out)
    gemm_k<<<dim3(8, 4, 16), 256, 0, stream>>>(
        xt, 512, 0, wb_cv1, 512, s_cv1, b_cv1,
        nullptr, 0, 0, yt, 512, 0, nullptr, nullptr, 1);
    // qkv from bb = y_t[:,:,256:]; V channels diverted to plane layout
    gemm_k<<<dim3(8, 4, 16), 256, 0, stream>>>(
        yt, 512, 256, wb_qkv, 256, s_qkv, b_qkv,
        nullptr, 0, 0, qkvt, 512, 0, nullptr, vsep, 0);
    // fused flash attention -> xa_t
    attn_k<<<dim3(16, 4, 16), 256, 0, stream>>>(qkvt, vsep, xat);
    // xa_t += dwconv3(v)
    pe_k<<<dim3(16, 16), 256, 0, stream>>>(vsep, W_pe, s_pe, b_pe, xat);
    // proj + residual, in-place into y_t[:,:,256:]
    gemm_k<<<dim3(8, 2, 16), 256, 0, stream>>>(
        xat, 256, 0, wb_proj, 256, s_proj, b_proj,
        yt, 512, 256, yt, 512, 256, nullptr, nullptr, 0);
    // ffn1
    gemm_k<<<dim3(8, 4, 16), 256, 0, stream>>>(
        yt, 512, 256, wb_ffn1, 256, s_ffn1, b_ffn1,
        nullptr, 0, 0, fft, 512, 0, nullptr, nullptr, 1);
    // ffn2 + residual, in-place into y_t[:,:,256:]
    gemm_k<<<dim3(8, 2, 16), 256, 0, stream>>>(
        fft, 512, 0, wb_ffn2, 512, s_ffn2, b_ffn2,
        yt, 512, 256, yt, 512, 256, nullptr, nullptr, 0);
    // cv2 on concat(a, bb) = y_t[:,:,0:512] -> d_out fp32 (b, 512, 1024)
    gemm_k<<<dim3(8, 4, 16), 256, 0, stream>>>(
        yt, 512, 0, wb_cv2, 512, s_cv2, b_cv2,
        nullptr, 0, 0, nullptr, 0, 0, (float*)d_out, nullptr, 1);
}

// Round 8
// 279.070 us; speedup vs baseline: 7.9250x; 1.0185x over previous
//
#include <hip/hip_runtime.h>

typedef unsigned short u16;
typedef __attribute__((ext_vector_type(8))) short short8;
typedef __attribute__((ext_vector_type(4))) float f32x4;
typedef __attribute__((ext_vector_type(4))) unsigned int uint4v;
typedef __attribute__((ext_vector_type(4))) unsigned short ushort4v;

#define N_PIX 1024
constexpr float SCALE = 0.17677669529663687f; // 32^-0.5

__device__ __forceinline__ float bf2f(u16 v) {
    unsigned u = ((unsigned)v) << 16;
    return __builtin_bit_cast(float, u);
}
__device__ __forceinline__ u16 f2bf(float f) {
    unsigned u = __builtin_bit_cast(unsigned, f);
    u += 0x7fff + ((u >> 16) & 1);
    return (u16)(u >> 16);
}
__device__ __forceinline__ float silu_f(float x) { return x / (1.f + __expf(-x)); }

__device__ __forceinline__ f32x4 mfma16(short8 a, short8 b, f32x4 c) {
    return __builtin_amdgcn_mfma_f32_16x16x32_bf16(a, b, c, 0, 0, 0);
}

__device__ __forceinline__ void gl_lds16(const u16* g, u16* l) {
    __builtin_amdgcn_global_load_lds(
        (const __attribute__((address_space(1))) unsigned int*)g,
        (__attribute__((address_space(3))) unsigned int*)l, 16, 0, 0);
}

// ---------------------------------------------------------------------------
// Weight fp32 -> bf16 conversion (6 segments, blockIdx.y selects)
// ---------------------------------------------------------------------------
__global__ void cvtw_k(const float* s0, u16* d0, int n0,
                       const float* s1, u16* d1, int n1,
                       const float* s2, u16* d2, int n2,
                       const float* s3, u16* d3, int n3,
                       const float* s4, u16* d4, int n4,
                       const float* s5, u16* d5, int n5)
{
    const float* sp = nullptr; u16* dp = nullptr; int n = 0;
    switch (blockIdx.y) {
        case 0: sp = s0; dp = d0; n = n0; break;
        case 1: sp = s1; dp = d1; n = n1; break;
        case 2: sp = s2; dp = d2; n = n2; break;
        case 3: sp = s3; dp = d3; n = n3; break;
        case 4: sp = s4; dp = d4; n = n4; break;
        case 5: sp = s5; dp = d5; n = n5; break;
    }
    for (int i = blockIdx.x * 256 + threadIdx.x; i < n; i += gridDim.x * 256)
        dp[i] = f2bf(sp[i]);
}

// ---------------------------------------------------------------------------
// x (b, 512, 1024) fp32 -> x_t (b, 1024, 512) bf16  (LDS-tiled transpose)
// ---------------------------------------------------------------------------
__global__ __launch_bounds__(256) void trans_k(const float* __restrict__ x, u16* __restrict__ xt)
{
    __shared__ float LT[64 * 65];
    const int tid = threadIdx.x;
    const int n0 = blockIdx.x * 64;
    const int c0 = blockIdx.y * 64;
    const int b  = blockIdx.z;
    const int w = tid >> 6, ln = tid & 63;
#pragma unroll
    for (int s = 0; s < 16; ++s) {
        int c = s * 4 + w;
        LT[c * 65 + ln] = x[((size_t)(b * 512 + c0 + c)) * N_PIX + n0 + ln];
    }
    __syncthreads();
#pragma unroll
    for (int s = 0; s < 16; ++s) {
        int n = s * 4 + w;
        xt[((size_t)(b * N_PIX + n0 + n)) * 512 + c0 + ln] = f2bf(LT[ln * 65 + n]);
    }
}

// ---------------------------------------------------------------------------
// bf16 MFMA GEMM for conv1x1: out_t[n][o] = act(s*Wx+b) (+res)
// Tile 128o x 128n, BK=32, 8 waves (4 o-strips x 2 n-halves), dbuf LDS,
// global_load_lds width-16. Activations transposed (b, n, c).
// out32 path: LDS-bounce transpose epilogue -> coalesced fp32 (b,o,n) writes.
// vsep path: o-blocks are heads; V channels (o&127 >= 64) to plane layout.
// ---------------------------------------------------------------------------
__global__ __launch_bounds__(512) void gemm_k(
    const u16* __restrict__ Xt, int xcs, int xcoff,
    const u16* __restrict__ Wb, int Cin,
    const float* __restrict__ sc, const float* __restrict__ bi,
    const u16* __restrict__ res, int rcs, int rcoff,
    u16* __restrict__ out, int ocs, int ocoff,
    float* __restrict__ out32,
    u16* __restrict__ vsep,
    int act)
{
    __shared__ __align__(16) u16 WT[2][128 * 32];
    __shared__ __align__(16) u16 XT[2][128 * 32];
    const int tid  = threadIdx.x;
    const int lane = tid & 63;
    const int w    = __builtin_amdgcn_readfirstlane(tid >> 6);
    const int wr = w & 3;        // o-strip of 32
    const int wc = w >> 2;       // n-half of 64
    const int n0 = blockIdx.x * 128;
    const int o0 = blockIdx.y * 128;
    const int b  = blockIdx.z;
    const int l4 = lane >> 4, l15 = lane & 15;

    // staging: thread stages one 16B granule; row = tid>>2, k-granule tid&3
    const int srow = tid >> 2;
    const int skc  = (tid & 3) * 8;
    const u16* wg = Wb + (size_t)(o0 + srow) * Cin + skc;
    const u16* xg = Xt + ((size_t)(b * N_PIX + n0 + srow)) * xcs + xcoff + skc;

    f32x4 acc[2][4];
#pragma unroll
    for (int i = 0; i < 2; ++i)
#pragma unroll
        for (int j = 0; j < 4; ++j) acc[i][j] = (f32x4){0.f, 0.f, 0.f, 0.f};

    const int nk = Cin >> 5;
    gl_lds16(wg, &WT[0][tid * 8]);
    gl_lds16(xg, &XT[0][tid * 8]);
    __syncthreads();

    for (int kk = 0; kk < nk; ++kk) {
        const int cur = kk & 1;
        if (kk + 1 < nk) {
            const int cc = (kk + 1) << 5;
            gl_lds16(wg + cc, &WT[cur ^ 1][tid * 8]);
            gl_lds16(xg + cc, &XT[cur ^ 1][tid * 8]);
        }
        short8 af[2], bfr[4];
#pragma unroll
        for (int i = 0; i < 2; ++i)
            af[i] = *(const short8*)&WT[cur][(wr * 32 + i * 16 + l15) * 32 + l4 * 8];
#pragma unroll
        for (int j = 0; j < 4; ++j)
            bfr[j] = *(const short8*)&XT[cur][(wc * 64 + j * 16 + l15) * 32 + l4 * 8];
#pragma unroll
        for (int i = 0; i < 2; ++i)
#pragma unroll
            for (int j = 0; j < 4; ++j)
                acc[i][j] = mfma16(af[i], bfr[j], acc[i][j]);
        __syncthreads();
    }

    if (out32) {
        // LDS-bounce transpose: 32 o-rows x 128 n fp32 per round via XT (16KB)
        const int Cout = gridDim.y * 128;
        float* eplds = (float*)XT;
        const int row = tid >> 4, cb = (tid & 15) * 8;
#pragma unroll
        for (int h = 0; h < 4; ++h) {
            if (wr == h) {
#pragma unroll
                for (int i = 0; i < 2; ++i)
#pragma unroll
                    for (int j = 0; j < 4; ++j)
#pragma unroll
                        for (int r = 0; r < 4; ++r) {
                            const int oo = i * 16 + l4 * 4 + r;   // 0..31
                            const int go = o0 + h * 32 + oo;
                            float v = acc[i][j][r] * sc[go] + bi[go];
                            if (act) v = silu_f(v);
                            eplds[oo * 128 + wc * 64 + j * 16 + l15] = v;
                        }
            }
            __syncthreads();
            const size_t gidx = ((size_t)b * Cout + o0 + h * 32 + row) * N_PIX + n0 + cb;
            f32x4 a0 = *(const f32x4*)&eplds[row * 128 + cb];
            f32x4 a1 = *(const f32x4*)&eplds[row * 128 + cb + 4];
            *(f32x4*)&out32[gidx]     = a0;
            *(f32x4*)&out32[gidx + 4] = a1;
            __syncthreads();
        }
        return;
    }

    const bool is_v = (vsep != nullptr) && (wr >= 2);
#pragma unroll
    for (int i = 0; i < 2; ++i) {
        const int ob = o0 + wr * 32 + i * 16 + l4 * 4;
        float s4[4], b4[4];
#pragma unroll
        for (int r = 0; r < 4; ++r) { s4[r] = sc[ob + r]; b4[r] = bi[ob + r]; }
#pragma unroll
        for (int j = 0; j < 4; ++j) {
            const int n = n0 + wc * 64 + j * 16 + l15;
            float v[4];
#pragma unroll
            for (int r = 0; r < 4; ++r) {
                v[r] = acc[i][j][r] * s4[r] + b4[r];
                if (act) v[r] = silu_f(v[r]);
            }
            if (is_v) {
                const int hh = ob >> 7;
                const int dv = (ob & 127) - 64;
                u16* vp = vsep + (((size_t)(b * 4 + hh)) * 64 + dv) * N_PIX + n;
#pragma unroll
                for (int r = 0; r < 4; ++r) vp[r * N_PIX] = f2bf(v[r]);
            } else {
                const size_t base = ((size_t)(b * N_PIX + n)) * ocs + ocoff + ob;
                if (res) {
                    ushort4v rr = *(const ushort4v*)&res[((size_t)(b * N_PIX + n)) * rcs + rcoff + ob];
#pragma unroll
                    for (int r = 0; r < 4; ++r) v[r] += bf2f(rr[r]);
                }
                ushort4v pk;
#pragma unroll
                for (int r = 0; r < 4; ++r) pk[r] = f2bf(v[r]);
                *(ushort4v*)&out[base] = pk;
            }
        }
    }
}

// ---------------------------------------------------------------------------
// Fused flash attention, latency-hidden version (unchanged from round 7).
// grid (16, 4, 16), 256 threads = 4 waves x 16 q-rows. KV tile = 64,
// double-buffered K/V LDS with async-STAGE split (T14), one barrier/tile.
// ---------------------------------------------------------------------------
__global__ __launch_bounds__(256) void attn_k(
    const u16* __restrict__ qkvt, const u16* __restrict__ vsep,
    u16* __restrict__ xat)
{
    __shared__ __align__(16) u16 KT[2][64 * 40];   // [m][d] pad 40
    __shared__ __align__(16) u16 VT[2][64 * 72];   // [dv][m] pad 72
    __shared__ __align__(16) u16 PL[4 * 16 * 72];  // per-wave P rows
    const int tid  = threadIdx.x;
    const int lane = tid & 63;
    const int w    = __builtin_amdgcn_readfirstlane(tid >> 6);
    const int l4 = lane >> 4, l15 = lane & 15;
    const int h = blockIdx.y, b = blockIdx.z;
    const int n0w = blockIdx.x * 64 + w * 16;
    u16* PLw = PL + w * 16 * 72;

    const short8 qf = *(const short8*)&qkvt[((size_t)(b * N_PIX + n0w + l15)) * 512 + h * 128 + l4 * 8];

    const int skr = tid >> 2, skc = (tid & 3) * 8;          // K: row, d-col
    const int svd = tid >> 3, svm = (tid & 7) * 8;          // V: dv (0..31), m-col
    const u16* kgbase = qkvt + ((size_t)(b * N_PIX + skr)) * 512 + h * 128 + 32 + skc;
    const u16* vgbase = vsep + (((size_t)(b * 4 + h)) * 64 + svd) * N_PIX + svm;

    float mrun[4], lrun[4];
#pragma unroll
    for (int r = 0; r < 4; ++r) { mrun[r] = -1e30f; lrun[r] = 0.f; }
    f32x4 accv[4];
#pragma unroll
    for (int d = 0; d < 4; ++d) accv[d] = (f32x4){0.f, 0.f, 0.f, 0.f};
    const f32x4 z4 = {0.f, 0.f, 0.f, 0.f};

    uint4v kreg = *(const uint4v*)(kgbase);
    uint4v vr0  = *(const uint4v*)(vgbase);
    uint4v vr1  = *(const uint4v*)(vgbase + 32 * N_PIX);

    for (int t = 0; t < 16; ++t) {
        const int cur = t & 1;
        *(uint4v*)&KT[cur][skr * 40 + skc] = kreg;
        *(uint4v*)&VT[cur][svd * 72 + svm] = vr0;
        *(uint4v*)&VT[cur][(svd + 32) * 72 + svm] = vr1;
        if (t < 15) {
            const int m1 = (t + 1) * 64;
            kreg = *(const uint4v*)(kgbase + (size_t)m1 * 512);
            vr0  = *(const uint4v*)(vgbase + m1);
            vr1  = *(const uint4v*)(vgbase + 32 * N_PIX + m1);
        }
        __syncthreads();

        f32x4 s[4];
        __builtin_amdgcn_s_setprio(1);
#pragma unroll
        for (int mt = 0; mt < 4; ++mt) {
            short8 kf = *(const short8*)&KT[cur][(mt * 16 + l15) * 40 + l4 * 8];
            s[mt] = mfma16(qf, kf, z4);
        }
        __builtin_amdgcn_s_setprio(0);

        float tm[4];
#pragma unroll
        for (int r = 0; r < 4; ++r) {
            float m_ = fmaxf(fmaxf(s[0][r], s[1][r]), fmaxf(s[2][r], s[3][r]));
            m_ = fmaxf(m_, __shfl_xor(m_, 1));
            m_ = fmaxf(m_, __shfl_xor(m_, 2));
            m_ = fmaxf(m_, __shfl_xor(m_, 4));
            m_ = fmaxf(m_, __shfl_xor(m_, 8));
            tm[r] = m_ * SCALE;
        }
#pragma unroll
        for (int r = 0; r < 4; ++r) {
            float mnew = fmaxf(mrun[r], tm[r]);
            float corr = __expf(mrun[r] - mnew);
            mrun[r] = mnew;
            lrun[r] *= corr;
#pragma unroll
            for (int d = 0; d < 4; ++d) accv[d][r] *= corr;
        }
#pragma unroll
        for (int mt = 0; mt < 4; ++mt)
#pragma unroll
            for (int r = 0; r < 4; ++r) {
                float p = __expf(s[mt][r] * SCALE - mrun[r]);
                lrun[r] += p;
                PLw[(l4 * 4 + r) * 72 + mt * 16 + l15] = f2bf(p);
            }

        __builtin_amdgcn_s_setprio(1);
#pragma unroll
        for (int mq = 0; mq < 2; ++mq) {
            short8 pa = *(const short8*)&PLw[l15 * 72 + mq * 32 + l4 * 8];
#pragma unroll
            for (int d = 0; d < 4; ++d) {
                short8 vf = *(const short8*)&VT[cur][(d * 16 + l15) * 72 + mq * 32 + l4 * 8];
                accv[d] = mfma16(pa, vf, accv[d]);
            }
        }
        __builtin_amdgcn_s_setprio(0);
    }

#pragma unroll
    for (int r = 0; r < 4; ++r) {
        float sum = lrun[r];
        sum += __shfl_xor(sum, 1);
        sum += __shfl_xor(sum, 2);
        sum += __shfl_xor(sum, 4);
        sum += __shfl_xor(sum, 8);
        lrun[r] = 1.f / sum;
    }
#pragma unroll
    for (int d = 0; d < 4; ++d)
#pragma unroll
        for (int r = 0; r < 4; ++r) {
            const int n = n0w + l4 * 4 + r;
            xat[((size_t)(b * N_PIX + n)) * 256 + h * 64 + d * 16 + l15] =
                f2bf(accv[d][r] * lrun[r]);
        }
}

// ---------------------------------------------------------------------------
// Depthwise 3x3 on V planes (v_sep), scale+bias, accumulate into xa_t.
// ---------------------------------------------------------------------------
__global__ __launch_bounds__(256) void pe_k(
    const u16* __restrict__ vsep, const float* __restrict__ Wpe,
    const float* __restrict__ spe, const float* __restrict__ bpe,
    u16* __restrict__ xat)
{
    const int t  = threadIdx.x;          // channel
    const int y0 = blockIdx.x * 2;
    const int b  = blockIdx.y;
    const u16* vp = vsep + ((size_t)(b * 256 + t)) * N_PIX;

    float rv[128];
#pragma unroll
    for (int rr = 0; rr < 4; ++rr) {
        const int yy = y0 - 1 + rr;
        if (yy >= 0 && yy < 32) {
#pragma unroll
            for (int g = 0; g < 4; ++g) {
                uint4v u = *(const uint4v*)&vp[yy * 32 + g * 8];
#pragma unroll
                for (int e = 0; e < 4; ++e) {
                    rv[rr * 32 + g * 8 + e * 2]     = bf2f((u16)(u[e] & 0xffff));
                    rv[rr * 32 + g * 8 + e * 2 + 1] = bf2f((u16)(u[e] >> 16));
                }
            }
        } else {
#pragma unroll
            for (int j = 0; j < 32; ++j) rv[rr * 32 + j] = 0.f;
        }
    }
    float w9[9];
#pragma unroll
    for (int i = 0; i < 9; ++i) w9[i] = Wpe[t * 9 + i];
    const float scv = spe[t], biv = bpe[t];
    u16* xp = xat + ((size_t)(b * N_PIX)) * 256 + t;

#pragma unroll
    for (int py = 0; py < 2; ++py)
#pragma unroll
        for (int px = 0; px < 32; ++px) {
            float a = 0.f;
#pragma unroll
            for (int ky = 0; ky < 3; ++ky) {
                const int lr = py + ky;
#pragma unroll
                for (int kx = 0; kx < 3; ++kx) {
                    const int xx = px + kx - 1;
                    if (xx >= 0 && xx < 32)
                        a = fmaf(w9[ky * 3 + kx], rv[lr * 32 + xx], a);
                }
            }
            const int n = (y0 + py) * 32 + px;
            u16* p = xp + (size_t)n * 256;
            *p = f2bf(bf2f(*p) + a * scv + biv);
        }
}

extern "C" void kernel_launch(void* const* d_in, const int* in_sizes, int n_in,
                              void* d_out, int out_size, void* d_ws, size_t ws_size,
                              hipStream_t stream)
{
    const float* x      = (const float*)d_in[0];
    const float* W_cv1  = (const float*)d_in[1];
    const float* s_cv1  = (const float*)d_in[2];
    const float* b_cv1  = (const float*)d_in[3];
    const float* W_qkv  = (const float*)d_in[4];
    const float* s_qkv  = (const float*)d_in[5];
    const float* b_qkv  = (const float*)d_in[6];
    const float* W_proj = (const float*)d_in[7];
    const float* s_proj = (const float*)d_in[8];
    const float* b_proj = (const float*)d_in[9];
    const float* W_pe   = (const float*)d_in[10];
    const float* s_pe   = (const float*)d_in[11];
    const float* b_pe   = (const float*)d_in[12];
    const float* W_ffn1 = (const float*)d_in[13];
    const float* s_ffn1 = (const float*)d_in[14];
    const float* b_ffn1 = (const float*)d_in[15];
    const float* W_ffn2 = (const float*)d_in[16];
    const float* s_ffn2 = (const float*)d_in[17];
    const float* b_ffn2 = (const float*)d_in[18];
    const float* W_cv2  = (const float*)d_in[19];
    const float* s_cv2  = (const float*)d_in[20];
    const float* b_cv2  = (const float*)d_in[21];

    u16* ws = (u16*)d_ws;
    u16* xt      = ws;                    // 16*1024*512
    u16* yt      = xt + 8388608;
    u16* qkvt    = yt + 8388608;
    u16* fft     = qkvt + 8388608;
    u16* vsep    = fft + 8388608;         // 16*256*1024
    u16* xat     = vsep + 4194304;        // 16*1024*256
    u16* wb_cv1  = xat + 4194304;
    u16* wb_qkv  = wb_cv1 + 262144;
    u16* wb_proj = wb_qkv + 131072;
    u16* wb_ffn1 = wb_proj + 65536;
    u16* wb_ffn2 = wb_ffn1 + 131072;
    u16* wb_cv2  = wb_ffn2 + 131072;

    cvtw_k<<<dim3(64, 6), 256, 0, stream>>>(
        W_cv1, wb_cv1, 512 * 512, W_qkv, wb_qkv, 512 * 256,
        W_proj, wb_proj, 256 * 256, W_ffn1, wb_ffn1, 512 * 256,
        W_ffn2, wb_ffn2, 256 * 512, W_cv2, wb_cv2, 512 * 512);
    trans_k<<<dim3(16, 8, 16), 256, 0, stream>>>(x, xt);

    // cv1: y_t = silu(W_cv1 x)   (512 out)
    gemm_k<<<dim3(8, 4, 16), 512, 0, stream>>>(
        xt, 512, 0, wb_cv1, 512, s_cv1, b_cv1,
        nullptr, 0, 0, yt, 512, 0, nullptr, nullptr, 1);
    // qkv from bb = y_t[:,:,256:]; V channels diverted to plane layout
    gemm_k<<<dim3(8, 4, 16), 512, 0, stream>>>(
        yt, 512, 256, wb_qkv, 256, s_qkv, b_qkv,
        nullptr, 0, 0, qkvt, 512, 0, nullptr, vsep, 0);
    // fused flash attention -> xa_t
    attn_k<<<dim3(16, 4, 16), 256, 0, stream>>>(qkvt, vsep, xat);
    // xa_t += dwconv3(v)
    pe_k<<<dim3(16, 16), 256, 0, stream>>>(vsep, W_pe, s_pe, b_pe, xat);
    // proj + residual, in-place into y_t[:,:,256:]
    gemm_k<<<dim3(8, 2, 16), 512, 0, stream>>>(
        xat, 256, 0, wb_proj, 256, s_proj, b_proj,
        yt, 512, 256, yt, 512, 256, nullptr, nullptr, 0);
    // ffn1
    gemm_k<<<dim3(8, 4, 16), 512, 0, stream>>>(
        yt, 512, 256, wb_ffn1, 256, s_ffn1, b_ffn1,
        nullptr, 0, 0, fft, 512, 0, nullptr, nullptr, 1);
    // ffn2 + residual, in-place into y_t[:,:,256:]
    gemm_k<<<dim3(8, 2, 16), 512, 0, stream>>>(
        fft, 512, 0, wb_ffn2, 512, s_ffn2, b_ffn2,
        yt, 512, 256, yt, 512, 256, nullptr, nullptr, 0);
    // cv2 on concat(a, bb) = y_t[:,:,0:512] -> d_out fp32 (b, 512, 1024)
    gemm_k<<<dim3(8, 4, 16), 512, 0, stream>>>(
        yt, 512, 0, wb_cv2, 512, s_cv2, b_cv2,
        nullptr, 0, 0, nullptr, 0, 0, (float*)d_out, nullptr, 1);
}